// Round 1
// baseline (349.296 us; speedup 1.0000x reference)
//
#include <hip/hip_runtime.h>
#include <math.h>

#define Bn 8
#define Hn 48
#define Wn 48
#define Cn 256
#define HW (Hn*Wn)          // 2304
#define PIX (Bn*HW)         // 18432
#define RADF 6.0f
#define PPB 4               // pixels per k3 block

typedef float vfloat4 __attribute__((ext_vector_type(4)));  // native vec for nontemporal builtins

// ---------------------------------------------------------------------------
// K1: per-pixel MLP.  16 lanes per pixel; lane o computes output o of the
// 256->16 layer via float4 dot products, then tanh, then each lane contributes
// tt[o]*w to the 16->2 heads, reduced with width-16 xor shuffles.
// NEW: fuses k2's statistics pass — each block reduces sum/sumsq of its 16
// pixels' (cv0,cv1) and atomically accumulates into per-batch stats[b*2+{0,1}]
// (stats zeroed by a 64B memsetAsync before launch).  All 16 pixels of a
// block belong to one batch (2304 %% 16 == 0).
// Writes: ws0[p] = (mean_x, mean_y, cv_raw0, cv_raw1); out_mean[p*2+{0,1}].
// ---------------------------------------------------------------------------
__global__ __launch_bounds__(256) void k1_mlp(
        const float* __restrict__ x,
        const float* __restrict__ map_w, const float* __restrict__ map_b,
        const float* __restrict__ mean_w, const float* __restrict__ mean_b,
        const float* __restrict__ cov_w,  const float* __restrict__ cov_b,
        float4* __restrict__ ws0, float* __restrict__ out_mean,
        float* __restrict__ stats) {
    int tid = threadIdx.x;
    int o = tid & 15;
    int p = blockIdx.x * 16 + (tid >> 4);   // grid exact: 18432/16 = 1152 blocks

    const float4* xr = (const float4*)(x + (size_t)p * Cn);
    const float4* wr = (const float4*)(map_w + (size_t)o * Cn);
    float acc = 0.f;
#pragma unroll 8
    for (int k = 0; k < Cn / 4; ++k) {
        float4 xv = xr[k], wv = wr[k];
        acc = fmaf(xv.x, wv.x, acc);
        acc = fmaf(xv.y, wv.y, acc);
        acc = fmaf(xv.z, wv.z, acc);
        acc = fmaf(xv.w, wv.w, acc);
    }
    float tt = tanhf(acc + map_b[o]);

    float m0 = tt * mean_w[o];
    float m1 = tt * mean_w[16 + o];
    float c0 = tt * cov_w[o];
    float c1 = tt * cov_w[16 + o];
#pragma unroll
    for (int off = 8; off; off >>= 1) {
        m0 += __shfl_xor(m0, off, 16);
        m1 += __shfl_xor(m1, off, 16);
        c0 += __shfl_xor(c0, off, 16);
        c1 += __shfl_xor(c1, off, 16);
    }

    __shared__ float ssum[16], ssq[16];
    if (o == 0) {
        int j = p % Wn;             // col -> coord[...,0]
        int i = (p / Wn) % Hn;      // row -> coord[...,1]
        float mx = m0 + mean_b[0] + (float)j;
        float my = m1 + mean_b[1] + (float)i;
        float cc0 = c0 + cov_b[0];
        float cc1 = c1 + cov_b[1];
        ws0[p] = make_float4(mx, my, cc0, cc1);
        out_mean[(size_t)p * 2]     = mx;
        out_mean[(size_t)p * 2 + 1] = my;
        int slot = tid >> 4;
        ssum[slot] = cc0 + cc1;
        ssq[slot]  = fmaf(cc0, cc0, cc1 * cc1);
    }
    __syncthreads();
    if (tid == 0) {
        float s = 0.f, q = 0.f;
#pragma unroll
        for (int k = 0; k < 16; ++k) { s += ssum[k]; q += ssq[k]; }
        int b = blockIdx.x / (HW / 16);   // 144 blocks per batch
        atomicAdd(&stats[b * 2],     s);  // device-scope by default (G12)
        atomicAdd(&stats[b * 2 + 1], q);
    }
}

// ---------------------------------------------------------------------------
// K3: heavy streaming pass. 256 threads, PPB=4 pixels per block (grid 4608).
// Phase 0 (NEW, absorbs old k2): threads 0..3 finalize their pixel — batch
// mean/var from stats, normalize, sigmoid*5+0.05, det -> out_det, Gaussian
// coefficients (-0.5*log2e/cv0, -0.5*log2e/cv1, 1/(6.28*sqrt(det))) into LDS.
// Phase 1: separable tables ex/ey per pixel in LDS (radius mask + 1/denom
// folded into ey).
// Phase 2: wave w streams pixel bp+w entirely (576 float4 = 9*64), so q is a
// compile-time shift of tid and LDS reads are broadcast / <=2-way (free).
// Non-temporal load/store: corr is touch-once, skip L2 allocation.
// ---------------------------------------------------------------------------
__global__ __launch_bounds__(256) void k3_mask(
        const float* __restrict__ corr,
        const float4* __restrict__ ws0,
        const float* __restrict__ stats,
        float* __restrict__ out_det,
        float* __restrict__ out) {
    int bp = blockIdx.x * PPB;
    int tid = threadIdx.x;
    __shared__ float ex[PPB][Wn];
    __shared__ float ey[PPB][Hn];
    __shared__ float4 mm[PPB];     // (mx, my, cv_raw0, cv_raw1)
    __shared__ float4 coef[PPB];   // (NL2E/cv0, NL2E/cv1, inv_denom, 0)

    // phase 0: per-pixel finalize (all 4 pixels of this block share a batch)
    if (tid < PPB) {
        int p = bp + tid;
        int b = p / HW;
        float4 r = ws0[p];
        float sum = stats[b * 2], sq = stats[b * 2 + 1];
        const float inv_n = 1.f / (2.f * HW);
        float mu   = sum * inv_n;
        float var  = sq * inv_n - mu * mu;
        float rstd = rsqrtf(var + 1e-5f);
        float z0 = (r.z - mu) * rstd;
        float z1 = (r.w - mu) * rstd;
        float cv0 = 5.f / (1.f + __expf(-z0)) + 0.05f;
        float cv1 = 5.f / (1.f + __expf(-z1)) + 0.05f;
        float det = cv0 * cv1;
        out_det[p] = det;
        const float NL2E = -0.72134752044448169f;   // -0.5 * log2(e)
        coef[tid] = make_float4(NL2E / cv0, NL2E / cv1,
                                1.f / (6.28f * sqrtf(det)), 0.f);
        mm[tid] = r;
    }
    __syncthreads();

    // phase 1: 384 table entries, 256 threads -> 2 rounds
    for (int e = tid; e < PPB * 96; e += 256) {
        int q = e / 96, rr = e - q * 96;
        float4 m = mm[q];
        float4 c = coef[q];
        if (rr < Wn) {
            float dx = (float)rr - m.x;
            ex[q][rr] = (fabsf(dx) <= RADF) ? exp2f(c.x * dx * dx) : 0.f;
        } else {
            int h2 = rr - Wn;
            float dy = (float)h2 - m.y;
            ey[q][h2] = (fabsf(dy) <= RADF) ? exp2f(c.y * dy * dy) * c.z : 0.f;
        }
    }
    __syncthreads();

    // phase 2: wave-per-pixel streaming
    int q    = tid >> 6;            // wave id == pixel index within block
    int lane = tid & 63;
    const vfloat4* src = (const vfloat4*)(corr + (size_t)(bp + q) * HW);
    vfloat4*       dst = (vfloat4*)(out + (size_t)(bp + q) * HW);
#pragma unroll
    for (int it = 0; it < 9; ++it) {
        int r  = it * 64 + lane;          // 0..575
        int h2 = r / 12;                  // 12 float4 per 48-wide row
        int w2 = (r - h2 * 12) * 4;
        vfloat4 v = __builtin_nontemporal_load(&src[r]);
        float eyv = ey[q][h2];
        v.x = fmaf(v.x, eyv * ex[q][w2],     v.x);
        v.y = fmaf(v.y, eyv * ex[q][w2 + 1], v.y);
        v.z = fmaf(v.z, eyv * ex[q][w2 + 2], v.z);
        v.w = fmaf(v.w, eyv * ex[q][w2 + 3], v.w);
        __builtin_nontemporal_store(v, &dst[r]);
    }
}

extern "C" void kernel_launch(void* const* d_in, const int* in_sizes, int n_in,
                              void* d_out, int out_size, void* d_ws, size_t ws_size,
                              hipStream_t stream) {
    const float* x      = (const float*)d_in[0];
    const float* corr   = (const float*)d_in[1];
    const float* map_w  = (const float*)d_in[2];
    const float* map_b  = (const float*)d_in[3];
    const float* mean_w = (const float*)d_in[4];
    const float* mean_b = (const float*)d_in[5];
    const float* cov_w  = (const float*)d_in[6];
    const float* cov_b  = (const float*)d_in[7];

    float* out       = (float*)d_out;
    float* out_corr1 = out;                                   // PIX*HW
    float* out_mean  = out + (size_t)PIX * HW;                // PIX*2
    float* out_det   = out_mean + (size_t)PIX * 2;            // PIX

    float4* ws0   = (float4*)d_ws;            // PIX float4
    float*  stats = (float*)(ws0 + PIX);      // 8 batches * 2 floats

    // zero the per-batch accumulators (64 B; stream-ordered, graph-capturable)
    hipMemsetAsync(stats, 0, Bn * 2 * sizeof(float), stream);

    k1_mlp<<<PIX / 16, 256, 0, stream>>>(x, map_w, map_b, mean_w, mean_b,
                                         cov_w, cov_b, ws0, out_mean, stats);
    k3_mask<<<PIX / PPB, 256, 0, stream>>>(corr, ws0, stats, out_det, out_corr1);
}